// Round 1
// baseline (2941.090 us; speedup 1.0000x reference)
//
#include <hip/hip_runtime.h>

#define NN 160000
#define DD 128
#define EE 600000
#define RR 8

// ---------------- generic GEMM: C[M x 128] = A[M x K] @ W[K x 128] (+bias) ----------------
// tile 64 rows x 128 cols, BK=32, 256 threads, each thread 8 rows x 4 cols.
__global__ __launch_bounds__(256) void gemm128(
    const float* __restrict__ A, const float* __restrict__ W,
    const float* __restrict__ bias, float* __restrict__ C,
    int M, int K) {
  __shared__ float As[32][65];
  __shared__ float Ws[32][132];
  const int tid = threadIdx.x;
  const int tx = tid & 31;       // col quad: cols 4*tx..4*tx+3
  const int ty = tid >> 5;       // row group: rows ty + 8*rr
  const int bm = blockIdx.x * 64;

  float4 acc[8];
#pragma unroll
  for (int i = 0; i < 8; ++i) acc[i] = make_float4(0.f, 0.f, 0.f, 0.f);

  for (int k0 = 0; k0 < K; k0 += 32) {
    // A tile 64x32 -> As[kk][m]
#pragma unroll
    for (int i = 0; i < 8; ++i) {
      int idx = tid + i * 256;
      int m = idx >> 5, kk = idx & 31;
      int row = bm + m;
      As[kk][m] = (row < M) ? A[(size_t)row * K + k0 + kk] : 0.f;
    }
    // W tile 32x128 -> Ws[kk][n]
#pragma unroll
    for (int i = 0; i < 16; ++i) {
      int idx = tid + i * 256;
      int kk = idx >> 7, n = idx & 127;
      Ws[kk][n] = W[(size_t)(k0 + kk) * 128 + n];
    }
    __syncthreads();
#pragma unroll
    for (int kk = 0; kk < 32; ++kk) {
      float4 w = *(const float4*)&Ws[kk][tx * 4];
#pragma unroll
      for (int rr = 0; rr < 8; ++rr) {
        float a = As[kk][ty + 8 * rr];
        acc[rr].x += a * w.x;
        acc[rr].y += a * w.y;
        acc[rr].z += a * w.z;
        acc[rr].w += a * w.w;
      }
    }
    __syncthreads();
  }

  float4 b = make_float4(0.f, 0.f, 0.f, 0.f);
  if (bias) b = *(const float4*)&bias[tx * 4];
#pragma unroll
  for (int rr = 0; rr < 8; ++rr) {
    int row = bm + ty + 8 * rr;
    if (row < M) {
      float4 v = acc[rr];
      v.x += b.x; v.y += b.y; v.z += b.z; v.w += b.w;
      *(float4*)&C[(size_t)row * 128 + tx * 4] = v;
    }
  }
}

// ---------------- edge-count per (dst, rel) ----------------
__global__ void count_kernel(const int* __restrict__ dst, const int* __restrict__ et,
                             float* __restrict__ cnt, int E) {
  int e = blockIdx.x * blockDim.x + threadIdx.x;
  if (e < E) atomicAdd(&cnt[(size_t)dst[e] * RR + et[e]], 1.0f);
}

__global__ void invcnt_kernel(float* __restrict__ cnt, int n) {
  int i = blockIdx.x * blockDim.x + threadIdx.x;
  if (i < n) cnt[i] = 1.0f / fmaxf(cnt[i], 1.0f);
}

// ---------------- scatter: out[dst] += hr[src] * invc[dst, r] for edges of type r ----------------
__global__ void scatter_kernel(const float* __restrict__ hr, const int* __restrict__ src,
                               const int* __restrict__ dst, const int* __restrict__ et,
                               const float* __restrict__ invc, float* __restrict__ out,
                               int r, int E) {
  int gwave = (blockIdx.x * blockDim.x + threadIdx.x) >> 6;
  int lane = threadIdx.x & 63;
  int nwaves = (gridDim.x * blockDim.x) >> 6;
  for (int e = gwave; e < E; e += nwaves) {
    if (et[e] != r) continue;
    int s = src[e], d = dst[e];
    float sc = invc[(size_t)d * RR + r];
    const float* hs = hr + (size_t)s * DD;
    float* od = out + (size_t)d * DD;
    atomicAdd(&od[lane], hs[lane] * sc);
    atomicAdd(&od[lane + 64], hs[lane + 64] * sc);
  }
}

__global__ void relu_kernel(float* __restrict__ x, int n4) {
  int i = blockIdx.x * blockDim.x + threadIdx.x;
  if (i < n4) {
    float4 v = ((float4*)x)[i];
    v.x = fmaxf(v.x, 0.f); v.y = fmaxf(v.y, 0.f);
    v.z = fmaxf(v.z, 0.f); v.w = fmaxf(v.w, 0.f);
    ((float4*)x)[i] = v;
  }
}

static inline void launch_gemm(const float* A, const float* W, const float* bias,
                               float* C, int M, int K, hipStream_t stream) {
  dim3 grid((M + 63) / 64);
  hipLaunchKernelGGL(gemm128, grid, dim3(256), 0, stream, A, W, bias, C, M, K);
}

extern "C" void kernel_launch(void* const* d_in, const int* in_sizes, int n_in,
                              void* d_out, int out_size, void* d_ws, size_t ws_size,
                              hipStream_t stream) {
  const float* x_user = (const float*)d_in[0];
  const float* x_food = (const float*)d_in[1];
  const float* x_ing  = (const float*)d_in[2];
  const float* x_cat  = (const float*)d_in[3];
  const float* x_hab  = (const float*)d_in[4];
  const int*   eidx   = (const int*)d_in[5];
  const int*   etype  = (const int*)d_in[6];
  const float* Wu = (const float*)d_in[7];
  const float* bu = (const float*)d_in[8];
  const float* Wf = (const float*)d_in[9];
  const float* bf = (const float*)d_in[10];
  const float* Wi = (const float*)d_in[11];
  const float* bi = (const float*)d_in[12];
  const float* Wc = (const float*)d_in[13];
  const float* bc = (const float*)d_in[14];
  const float* Wh = (const float*)d_in[15];
  const float* bh = (const float*)d_in[16];
  const float* W1    = (const float*)d_in[17];
  const float* root1 = (const float*)d_in[18];
  const float* bias1 = (const float*)d_in[19];
  const float* W2    = (const float*)d_in[20];
  const float* root2 = (const float*)d_in[21];
  const float* bias2 = (const float*)d_in[22];

  const int* src = eidx;
  const int* dst = eidx + EE;

  float* out = (float*)d_out;            // doubles as x_all during phase A / conv1
  float* h   = (float*)d_ws;             // 160000*128
  float* hr  = h + (size_t)NN * DD;      // 160000*128
  float* cnt = hr + (size_t)NN * DD;     // 160000*8

  // ---- Phase A: input projections -> x_all (stored in d_out) ----
  launch_gemm(x_user, Wu, bu, out + (size_t)0 * DD,      50000, 256, stream);
  launch_gemm(x_food, Wf, bf, out + (size_t)50000 * DD,  50000, 128, stream);
  launch_gemm(x_ing,  Wi, bi, out + (size_t)100000 * DD, 50000, 128, stream);
  launch_gemm(x_cat,  Wc, bc, out + (size_t)150000 * DD, 5000,  64,  stream);
  launch_gemm(x_hab,  Wh, bh, out + (size_t)155000 * DD, 5000,  64,  stream);

  // ---- edge counts (shared by both convs) ----
  hipMemsetAsync(cnt, 0, (size_t)NN * RR * sizeof(float), stream);
  hipLaunchKernelGGL(count_kernel, dim3((EE + 255) / 256), dim3(256), 0, stream,
                     dst, etype, cnt, EE);
  hipLaunchKernelGGL(invcnt_kernel, dim3((NN * RR + 255) / 256), dim3(256), 0, stream,
                     cnt, NN * RR);

  // ---- conv1: in = x_all (d_out), result -> h ----
  launch_gemm(out, root1, bias1, h, NN, DD, stream);
  for (int r = 0; r < RR; ++r) {
    launch_gemm(out, W1 + (size_t)r * DD * DD, nullptr, hr, NN, DD, stream);
    hipLaunchKernelGGL(scatter_kernel, dim3(2048), dim3(256), 0, stream,
                       hr, src, dst, etype, cnt, h, r, EE);
  }
  hipLaunchKernelGGL(relu_kernel, dim3((NN * DD / 4 + 255) / 256), dim3(256), 0, stream,
                     h, NN * DD / 4);

  // ---- conv2: in = h, result -> d_out ----
  launch_gemm(h, root2, bias2, out, NN, DD, stream);
  for (int r = 0; r < RR; ++r) {
    launch_gemm(h, W2 + (size_t)r * DD * DD, nullptr, hr, NN, DD, stream);
    hipLaunchKernelGGL(scatter_kernel, dim3(2048), dim3(256), 0, stream,
                       hr, src, dst, etype, cnt, out, r, EE);
  }
}

// Round 2
// 1815.820 us; speedup vs baseline: 1.6197x; 1.6197x over previous
//
#include <hip/hip_runtime.h>

typedef unsigned short ushort_t;
typedef unsigned int uint_t;
typedef __attribute__((ext_vector_type(8))) __bf16 bf16x8;
typedef __attribute__((ext_vector_type(4))) float f32x4;
typedef __attribute__((ext_vector_type(4))) uint_t uint4v;

#define NN 160000
#define DD 128
#define EE 600000
#define RR 8

__device__ __forceinline__ ushort_t f2b(float f) {
  uint_t u = __float_as_uint(f);
  u = u + 0x7fffu + ((u >> 16) & 1u);   // round-nearest-even
  return (ushort_t)(u >> 16);
}
__device__ __forceinline__ float b2f(ushort_t u) {
  return __uint_as_float(((uint_t)u) << 16);
}

// ---------------- f32 -> bf16 conversion (n multiple of 4) ----------------
__global__ void f32_to_bf16_kernel(const float* __restrict__ src,
                                   ushort_t* __restrict__ dst, int n4) {
  int i = blockIdx.x * blockDim.x + threadIdx.x;
  if (i < n4) {
    float4 v = ((const float4*)src)[i];
    uint2 o;
    o.x = (uint_t)f2b(v.x) | ((uint_t)f2b(v.y) << 16);
    o.y = (uint_t)f2b(v.z) | ((uint_t)f2b(v.w) << 16);
    ((uint2*)dst)[i] = o;
  }
}

// ---------------- relu + f32 -> bf16 ----------------
__global__ void relu_b16_kernel(const float* __restrict__ src,
                                ushort_t* __restrict__ dst, int n4) {
  int i = blockIdx.x * blockDim.x + threadIdx.x;
  if (i < n4) {
    float4 v = ((const float4*)src)[i];
    v.x = fmaxf(v.x, 0.f); v.y = fmaxf(v.y, 0.f);
    v.z = fmaxf(v.z, 0.f); v.w = fmaxf(v.w, 0.f);
    uint2 o;
    o.x = (uint_t)f2b(v.x) | ((uint_t)f2b(v.y) << 16);
    o.y = (uint_t)f2b(v.z) | ((uint_t)f2b(v.w) << 16);
    ((uint2*)dst)[i] = o;
  }
}

// ---------------- weight convert + transpose: src [nmat][K][128] f32 -> dst [nmat][128][K] bf16 ----------------
__global__ void wconv_kernel(const float* __restrict__ src,
                             ushort_t* __restrict__ dst, int K, int nmat) {
  int i = blockIdx.x * blockDim.x + threadIdx.x;
  int total = nmat * K * 128;
  if (i >= total) return;
  int m = i / (K * 128), rem = i % (K * 128);
  int k = rem / 128, n = rem % 128;
  dst[(size_t)m * 128 * K + (size_t)n * K + k] = f2b(src[i]);
}

// ---------------- bf16 MFMA GEMM: C[M x 128] = A[M x K](bf16) @ W[K x 128](bf16, given transposed) ----------------
// block: 128 rows x 128 cols, 256 threads (4 waves), BK=128, XOR-swizzled LDS.
template <bool OBF>
__global__ __launch_bounds__(256, 2) void gemm_bf16(
    const ushort_t* __restrict__ A, const ushort_t* __restrict__ WT,
    const float* __restrict__ bias, void* __restrict__ Cout, int M, int K) {
  __shared__ ushort_t As[128 * 128];
  __shared__ ushort_t Ws[128 * 128];
  const int tid = threadIdx.x;
  const int bm = blockIdx.x * 128;
  const int wave = tid >> 6, lane = tid & 63;
  const int lr = lane & 15;   // row (A) / col (B,D) within 16x16 tile
  const int lg = lane >> 4;   // k-group / D-row-group

  f32x4 acc[2][8];
#pragma unroll
  for (int mt = 0; mt < 2; ++mt)
#pragma unroll
    for (int nt = 0; nt < 8; ++nt) acc[mt][nt] = {0.f, 0.f, 0.f, 0.f};

  for (int k0 = 0; k0 < K; k0 += 128) {
    // stage A tile: rows (bm..bm+127) x k (k0..k0+127), swizzled
#pragma unroll
    for (int it = 0; it < 8; ++it) {
      int row = it * 16 + (tid >> 4);
      int c = tid & 15;
      uint4v val = {0, 0, 0, 0};
      int grow = bm + row, gk = k0 + c * 8;
      if (grow < M && gk < K)
        val = *(const uint4v*)(A + (size_t)grow * K + gk);
      *(uint4v*)&As[row * 128 + ((c ^ (row & 7)) * 8)] = val;
    }
    // stage WT tile: n rows 0..127 x k (k0..k0+127), swizzled
#pragma unroll
    for (int it = 0; it < 8; ++it) {
      int n = it * 16 + (tid >> 4);
      int c = tid & 15;
      uint4v val = {0, 0, 0, 0};
      int gk = k0 + c * 8;
      if (gk < K)
        val = *(const uint4v*)(WT + (size_t)n * K + gk);
      *(uint4v*)&Ws[n * 128 + ((c ^ (n & 7)) * 8)] = val;
    }
    __syncthreads();
#pragma unroll
    for (int ks = 0; ks < 4; ++ks) {
      int chunk = ks * 4 + lg;
      bf16x8 af[2], bfr[8];
#pragma unroll
      for (int mt = 0; mt < 2; ++mt) {
        int row = wave * 32 + mt * 16 + lr;
        af[mt] = *(const bf16x8*)&As[row * 128 + ((chunk ^ (row & 7)) * 8)];
      }
#pragma unroll
      for (int nt = 0; nt < 8; ++nt) {
        int n = nt * 16 + lr;
        bfr[nt] = *(const bf16x8*)&Ws[n * 128 + ((chunk ^ (n & 7)) * 8)];
      }
#pragma unroll
      for (int mt = 0; mt < 2; ++mt)
#pragma unroll
        for (int nt = 0; nt < 8; ++nt)
          acc[mt][nt] = __builtin_amdgcn_mfma_f32_16x16x32_bf16(
              af[mt], bfr[nt], acc[mt][nt], 0, 0, 0);
    }
    __syncthreads();
  }

  float bv[8];
#pragma unroll
  for (int nt = 0; nt < 8; ++nt) bv[nt] = bias ? bias[nt * 16 + lr] : 0.f;

#pragma unroll
  for (int mt = 0; mt < 2; ++mt) {
    int rbase = bm + wave * 32 + mt * 16 + lg * 4;
#pragma unroll
    for (int i = 0; i < 4; ++i) {
      int row = rbase + i;
      if (row >= M) continue;
#pragma unroll
      for (int nt = 0; nt < 8; ++nt) {
        int col = nt * 16 + lr;
        float v = acc[mt][nt][i] + bv[nt];
        if (OBF)
          ((ushort_t*)Cout)[(size_t)row * 128 + col] = f2b(v);
        else
          ((float*)Cout)[(size_t)row * 128 + col] = v;
      }
    }
  }
}

// ---------------- edge-count per (dst, rel) ----------------
__global__ void count_kernel(const int* __restrict__ dst, const int* __restrict__ et,
                             float* __restrict__ cnt, int E) {
  int e = blockIdx.x * blockDim.x + threadIdx.x;
  if (e < E) atomicAdd(&cnt[(size_t)dst[e] * RR + et[e]], 1.0f);
}

__global__ void invcnt_kernel(float* __restrict__ cnt, int n) {
  int i = blockIdx.x * blockDim.x + threadIdx.x;
  if (i < n) cnt[i] = 1.0f / fmaxf(cnt[i], 1.0f);
}

// ---------------- scatter: out[dst] += b2f(hr[src]) * invc[dst, r] for edges of type r ----------------
__global__ void scatter_kernel(const ushort_t* __restrict__ hr, const int* __restrict__ src,
                               const int* __restrict__ dst, const int* __restrict__ et,
                               const float* __restrict__ invc, float* __restrict__ out,
                               int r, int E) {
  int gwave = (blockIdx.x * blockDim.x + threadIdx.x) >> 6;
  int lane = threadIdx.x & 63;
  int nwaves = (gridDim.x * blockDim.x) >> 6;
  for (int e = gwave; e < E; e += nwaves) {
    if (et[e] != r) continue;
    int s = src[e], d = dst[e];
    float sc = invc[(size_t)d * RR + r];
    uint_t v = ((const uint_t*)(hr + (size_t)s * DD))[lane];
    float* od = out + (size_t)d * DD + lane * 2;
    atomicAdd(od, b2f((ushort_t)(v & 0xffff)) * sc);
    atomicAdd(od + 1, b2f((ushort_t)(v >> 16)) * sc);
  }
}

static inline void launch_gemm_f32out(const ushort_t* A, const ushort_t* WT, const float* bias,
                                      float* C, int M, int K, hipStream_t stream) {
  hipLaunchKernelGGL((gemm_bf16<false>), dim3((M + 127) / 128), dim3(256), 0, stream,
                     A, WT, bias, (void*)C, M, K);
}
static inline void launch_gemm_b16out(const ushort_t* A, const ushort_t* WT, const float* bias,
                                      ushort_t* C, int M, int K, hipStream_t stream) {
  hipLaunchKernelGGL((gemm_bf16<true>), dim3((M + 127) / 128), dim3(256), 0, stream,
                     A, WT, bias, (void*)C, M, K);
}
static inline void launch_conv(const float* s, ushort_t* d, int n, hipStream_t stream) {
  int n4 = n / 4;
  hipLaunchKernelGGL(f32_to_bf16_kernel, dim3((n4 + 255) / 256), dim3(256), 0, stream, s, d, n4);
}
static inline void launch_wconv(const float* s, ushort_t* d, int K, int nmat, hipStream_t stream) {
  int total = nmat * K * 128;
  hipLaunchKernelGGL(wconv_kernel, dim3((total + 255) / 256), dim3(256), 0, stream, s, d, K, nmat);
}

extern "C" void kernel_launch(void* const* d_in, const int* in_sizes, int n_in,
                              void* d_out, int out_size, void* d_ws, size_t ws_size,
                              hipStream_t stream) {
  const float* x_user = (const float*)d_in[0];
  const float* x_food = (const float*)d_in[1];
  const float* x_ing  = (const float*)d_in[2];
  const float* x_cat  = (const float*)d_in[3];
  const float* x_hab  = (const float*)d_in[4];
  const int*   eidx   = (const int*)d_in[5];
  const int*   etype  = (const int*)d_in[6];
  const float* Wu = (const float*)d_in[7];
  const float* bu = (const float*)d_in[8];
  const float* Wf = (const float*)d_in[9];
  const float* bfp = (const float*)d_in[10];
  const float* Wi = (const float*)d_in[11];
  const float* bi = (const float*)d_in[12];
  const float* Wc = (const float*)d_in[13];
  const float* bc = (const float*)d_in[14];
  const float* Wh = (const float*)d_in[15];
  const float* bh = (const float*)d_in[16];
  const float* W1    = (const float*)d_in[17];
  const float* root1 = (const float*)d_in[18];
  const float* bias1 = (const float*)d_in[19];
  const float* W2    = (const float*)d_in[20];
  const float* root2 = (const float*)d_in[21];
  const float* bias2 = (const float*)d_in[22];

  const int* src = eidx;
  const int* dst = eidx + EE;

  char* ws = (char*)d_ws;
  ushort_t* xb   = (ushort_t*)(ws);                       // 160000*128 bf16 (40.96 MB)
  float*    h    = (float*)(ws + 40960000);               // 160000*128 f32  (81.92 MB)
  ushort_t* hr   = (ushort_t*)(ws + 122880000);           // 160000*128 bf16 (40.96 MB), also input staging
  float*    invc = (float*)(ws + 163840000);              // 160000*8 f32 (5.12 MB)
  ushort_t* wbuf = (ushort_t*)(ws + 168960000);           // 753664 B of bf16 weights

  ushort_t* WuT = wbuf;            // 128x256
  ushort_t* WfT = wbuf + 32768;    // 128x128
  ushort_t* WiT = wbuf + 49152;
  ushort_t* WcT = wbuf + 65536;    // 128x64
  ushort_t* WhT = wbuf + 73728;
  ushort_t* r1T = wbuf + 81920;    // 128x128
  ushort_t* r2T = wbuf + 98304;
  ushort_t* W1T = wbuf + 114688;   // 8 x 128x128
  ushort_t* W2T = wbuf + 245760;

  float* out = (float*)d_out;

  // ---- weight conversion + transpose ----
  launch_wconv(Wu, WuT, 256, 1, stream);
  launch_wconv(Wf, WfT, 128, 1, stream);
  launch_wconv(Wi, WiT, 128, 1, stream);
  launch_wconv(Wc, WcT, 64, 1, stream);
  launch_wconv(Wh, WhT, 64, 1, stream);
  launch_wconv(root1, r1T, 128, 1, stream);
  launch_wconv(root2, r2T, 128, 1, stream);
  launch_wconv(W1, W1T, 128, 8, stream);
  launch_wconv(W2, W2T, 128, 8, stream);

  // ---- Phase A: input projections -> xb (bf16 x_all), staging in hr ----
  ushort_t* stg = hr;
  launch_conv(x_user, stg, 50000 * 256, stream);
  launch_gemm_b16out(stg, WuT, bu, xb + (size_t)0 * DD, 50000, 256, stream);
  launch_conv(x_food, stg, 50000 * 128, stream);
  launch_conv(x_ing, stg + (size_t)50000 * 128, 50000 * 128, stream);
  launch_gemm_b16out(stg, WfT, bfp, xb + (size_t)50000 * DD, 50000, 128, stream);
  launch_gemm_b16out(stg + (size_t)50000 * 128, WiT, bi, xb + (size_t)100000 * DD, 50000, 128, stream);
  launch_conv(x_cat, stg, 5000 * 64, stream);
  launch_conv(x_hab, stg + (size_t)5000 * 64, 5000 * 64, stream);
  launch_gemm_b16out(stg, WcT, bc, xb + (size_t)150000 * DD, 5000, 64, stream);
  launch_gemm_b16out(stg + (size_t)5000 * 64, WhT, bh, xb + (size_t)155000 * DD, 5000, 64, stream);

  // ---- edge counts (shared by both convs) ----
  hipMemsetAsync(invc, 0, (size_t)NN * RR * sizeof(float), stream);
  hipLaunchKernelGGL(count_kernel, dim3((EE + 255) / 256), dim3(256), 0, stream,
                     dst, etype, invc, EE);
  hipLaunchKernelGGL(invcnt_kernel, dim3((NN * RR + 255) / 256), dim3(256), 0, stream,
                     invc, NN * RR);

  // ---- conv1: in = xb, result -> h (f32) ----
  launch_gemm_f32out(xb, r1T, bias1, h, NN, 128, stream);
  for (int r = 0; r < RR; ++r) {
    launch_gemm_b16out(xb, W1T + (size_t)r * 16384, nullptr, hr, NN, 128, stream);
    hipLaunchKernelGGL(scatter_kernel, dim3(2048), dim3(256), 0, stream,
                       hr, src, dst, etype, invc, h, r, EE);
  }
  // relu + convert -> xb (conv2 input)
  hipLaunchKernelGGL(relu_b16_kernel, dim3((NN * DD / 4 + 255) / 256), dim3(256), 0, stream,
                     h, xb, NN * DD / 4);

  // ---- conv2: in = xb, result -> d_out (f32) ----
  launch_gemm_f32out(xb, r2T, bias2, out, NN, 128, stream);
  for (int r = 0; r < RR; ++r) {
    launch_gemm_b16out(xb, W2T + (size_t)r * 16384, nullptr, hr, NN, 128, stream);
    hipLaunchKernelGGL(scatter_kernel, dim3(2048), dim3(256), 0, stream,
                       hr, src, dst, etype, invc, out, r, EE);
  }
}

// Round 3
// 955.841 us; speedup vs baseline: 3.0770x; 1.8997x over previous
//
#include <hip/hip_runtime.h>

typedef unsigned short ushort_t;
typedef unsigned int uint_t;
typedef __attribute__((ext_vector_type(8))) __bf16 bf16x8;
typedef __attribute__((ext_vector_type(4))) float f32x4;
typedef __attribute__((ext_vector_type(4))) uint_t uint4v;

#define NN 160000
#define DD 128
#define EE 600000
#define RR 8
#define NRR (NN * RR)          // 1,280,000 pairs
#define CHUNK_CAP 250000       // compact rows per 4-relation chunk (mean ~239.6K, +27 sigma)

__device__ __forceinline__ ushort_t f2b(float f) {
  uint_t u = __float_as_uint(f);
  u = u + 0x7fffu + ((u >> 16) & 1u);   // round-nearest-even
  return (ushort_t)(u >> 16);
}
__device__ __forceinline__ float b2f(ushort_t u) {
  return __uint_as_float(((uint_t)u) << 16);
}

// ---------------- f32 -> bf16 conversion (n multiple of 4) ----------------
__global__ void f32_to_bf16_kernel(const float* __restrict__ src,
                                   ushort_t* __restrict__ dst, int n4) {
  int i = blockIdx.x * blockDim.x + threadIdx.x;
  if (i < n4) {
    float4 v = ((const float4*)src)[i];
    uint2 o;
    o.x = (uint_t)f2b(v.x) | ((uint_t)f2b(v.y) << 16);
    o.y = (uint_t)f2b(v.z) | ((uint_t)f2b(v.w) << 16);
    ((uint2*)dst)[i] = o;
  }
}

// ---------------- weight convert + transpose: src [nmat][K][128] f32 -> dst [nmat][128][K] bf16 ----------------
__global__ void wconv_kernel(const float* __restrict__ src,
                             ushort_t* __restrict__ dst, int K, int nmat) {
  int i = blockIdx.x * blockDim.x + threadIdx.x;
  int total = nmat * K * 128;
  if (i >= total) return;
  int m = i / (K * 128), rem = i % (K * 128);
  int k = rem / 128, n = rem % 128;
  dst[(size_t)m * 128 * K + (size_t)n * K + k] = f2b(src[i]);
}

// ---------------- bf16 MFMA GEMM: C[M x 128] = A[M x K](bf16) @ WT[128 x K](bf16) ----------------
template <bool OBF>
__global__ __launch_bounds__(256, 2) void gemm_bf16(
    const ushort_t* __restrict__ A, const ushort_t* __restrict__ WT,
    const float* __restrict__ bias, void* __restrict__ Cout, int M, int K) {
  __shared__ ushort_t As[128 * 128];
  __shared__ ushort_t Ws[128 * 128];
  const int tid = threadIdx.x;
  const int bm = blockIdx.x * 128;
  const int wave = tid >> 6, lane = tid & 63;
  const int lr = lane & 15;
  const int lg = lane >> 4;

  f32x4 acc[2][8];
#pragma unroll
  for (int mt = 0; mt < 2; ++mt)
#pragma unroll
    for (int nt = 0; nt < 8; ++nt) acc[mt][nt] = {0.f, 0.f, 0.f, 0.f};

  for (int k0 = 0; k0 < K; k0 += 128) {
#pragma unroll
    for (int it = 0; it < 8; ++it) {
      int row = it * 16 + (tid >> 4);
      int c = tid & 15;
      uint4v val = {0, 0, 0, 0};
      int grow = bm + row, gk = k0 + c * 8;
      if (grow < M && gk < K)
        val = *(const uint4v*)(A + (size_t)grow * K + gk);
      *(uint4v*)&As[row * 128 + ((c ^ (row & 7)) * 8)] = val;
    }
#pragma unroll
    for (int it = 0; it < 8; ++it) {
      int n = it * 16 + (tid >> 4);
      int c = tid & 15;
      uint4v val = {0, 0, 0, 0};
      int gk = k0 + c * 8;
      if (gk < K)
        val = *(const uint4v*)(WT + (size_t)n * K + gk);
      *(uint4v*)&Ws[n * 128 + ((c ^ (n & 7)) * 8)] = val;
    }
    __syncthreads();
#pragma unroll
    for (int ks = 0; ks < 4; ++ks) {
      int chunk = ks * 4 + lg;
      bf16x8 af[2], bfr[8];
#pragma unroll
      for (int mt = 0; mt < 2; ++mt) {
        int row = wave * 32 + mt * 16 + lr;
        af[mt] = *(const bf16x8*)&As[row * 128 + ((chunk ^ (row & 7)) * 8)];
      }
#pragma unroll
      for (int nt = 0; nt < 8; ++nt) {
        int n = nt * 16 + lr;
        bfr[nt] = *(const bf16x8*)&Ws[n * 128 + ((chunk ^ (n & 7)) * 8)];
      }
#pragma unroll
      for (int mt = 0; mt < 2; ++mt)
#pragma unroll
        for (int nt = 0; nt < 8; ++nt)
          acc[mt][nt] = __builtin_amdgcn_mfma_f32_16x16x32_bf16(
              af[mt], bfr[nt], acc[mt][nt], 0, 0, 0);
    }
    __syncthreads();
  }

  float bv[8];
#pragma unroll
  for (int nt = 0; nt < 8; ++nt) bv[nt] = bias ? bias[nt * 16 + lr] : 0.f;

#pragma unroll
  for (int mt = 0; mt < 2; ++mt) {
    int rbase = bm + wave * 32 + mt * 16 + lg * 4;
#pragma unroll
    for (int i = 0; i < 4; ++i) {
      int row = rbase + i;
      if (row >= M) continue;
#pragma unroll
      for (int nt = 0; nt < 8; ++nt) {
        int col = nt * 16 + lr;
        float v = acc[mt][nt][i] + bv[nt];
        if (OBF)
          ((ushort_t*)Cout)[(size_t)row * 128 + col] = f2b(v);
        else
          ((float*)Cout)[(size_t)row * 128 + col] = v;
      }
    }
  }
}

// ---------------- compact per-relation GEMM, K=128, in-place on tC (bf16) ----------------
__global__ __launch_bounds__(256, 2) void gemm_rel(
    ushort_t* __restrict__ tC, const ushort_t* __restrict__ WT_all,
    const int* __restrict__ rowstart, int c) {
  __shared__ ushort_t As[128 * 128];
  __shared__ ushort_t Ws[128 * 128];
  const int rel = c * 4 + blockIdx.y;
  const int base = rowstart[c * 4];
  const int start = rowstart[rel] - base;
  const int end = rowstart[rel + 1] - base;
  const int bm = start + blockIdx.x * 128;
  if (bm >= end) return;
  const ushort_t* WT = WT_all + (size_t)rel * 16384;
  const int tid = threadIdx.x;
  const int wave = tid >> 6, lane = tid & 63;
  const int lr = lane & 15, lg = lane >> 4;

#pragma unroll
  for (int it = 0; it < 8; ++it) {
    int row = it * 16 + (tid >> 4);
    int cc = tid & 15;
    uint4v val = {0, 0, 0, 0};
    int grow = bm + row;
    if (grow < end)
      val = *(const uint4v*)(tC + (size_t)grow * 128 + cc * 8);
    *(uint4v*)&As[row * 128 + ((cc ^ (row & 7)) * 8)] = val;
  }
#pragma unroll
  for (int it = 0; it < 8; ++it) {
    int n = it * 16 + (tid >> 4);
    int cc = tid & 15;
    uint4v val = *(const uint4v*)(WT + (size_t)n * 128 + cc * 8);
    *(uint4v*)&Ws[n * 128 + ((cc ^ (n & 7)) * 8)] = val;
  }
  __syncthreads();

  f32x4 acc[2][8];
#pragma unroll
  for (int mt = 0; mt < 2; ++mt)
#pragma unroll
    for (int nt = 0; nt < 8; ++nt) acc[mt][nt] = {0.f, 0.f, 0.f, 0.f};

#pragma unroll
  for (int ks = 0; ks < 4; ++ks) {
    int chunk = ks * 4 + lg;
    bf16x8 af[2], bfr[8];
#pragma unroll
    for (int mt = 0; mt < 2; ++mt) {
      int row = wave * 32 + mt * 16 + lr;
      af[mt] = *(const bf16x8*)&As[row * 128 + ((chunk ^ (row & 7)) * 8)];
    }
#pragma unroll
    for (int nt = 0; nt < 8; ++nt) {
      int n = nt * 16 + lr;
      bfr[nt] = *(const bf16x8*)&Ws[n * 128 + ((chunk ^ (n & 7)) * 8)];
    }
#pragma unroll
    for (int mt = 0; mt < 2; ++mt)
#pragma unroll
      for (int nt = 0; nt < 8; ++nt)
        acc[mt][nt] = __builtin_amdgcn_mfma_f32_16x16x32_bf16(
            af[mt], bfr[nt], acc[mt][nt], 0, 0, 0);
  }
  __syncthreads();

#pragma unroll
  for (int mt = 0; mt < 2; ++mt) {
    int rbase = bm + wave * 32 + mt * 16 + lg * 4;
#pragma unroll
    for (int i = 0; i < 4; ++i) {
      int row = rbase + i;
      if (row >= end) continue;
#pragma unroll
      for (int nt = 0; nt < 8; ++nt)
        tC[(size_t)row * 128 + nt * 16 + lr] = f2b(acc[mt][nt][i]);
    }
  }
}

// ---------------- edge bucketing ----------------
__global__ void count_kernel(const int* __restrict__ dstv, const int* __restrict__ et,
                             int* __restrict__ cnt, int E) {
  int e = blockIdx.x * blockDim.x + threadIdx.x;
  if (e < E) atomicAdd(&cnt[(size_t)et[e] * NN + dstv[e]], 1);
}

__global__ __launch_bounds__(256) void scan1_kernel(const int* __restrict__ in, int* __restrict__ out,
                                                    int* __restrict__ partials, int n, int binarize) {
  __shared__ int sums[256];
  int tid = threadIdx.x;
  int base = blockIdx.x * 2048 + tid * 8;
  int v[8];
  int s = 0;
#pragma unroll
  for (int i = 0; i < 8; ++i) {
    int idx = base + i;
    int x = (idx < n) ? in[idx] : 0;
    if (binarize) x = (x > 0) ? 1 : 0;
    v[i] = s;
    s += x;
  }
  sums[tid] = s;
  __syncthreads();
  for (int off = 1; off < 256; off <<= 1) {
    int t = (tid >= off) ? sums[tid - off] : 0;
    __syncthreads();
    sums[tid] += t;
    __syncthreads();
  }
  int excl = (tid == 0) ? 0 : sums[tid - 1];
  if (tid == 255) partials[blockIdx.x] = sums[255];
#pragma unroll
  for (int i = 0; i < 8; ++i) {
    int idx = base + i;
    if (idx < n) out[idx] = excl + v[i];
  }
}

__global__ __launch_bounds__(256) void scan2_kernel(int* __restrict__ partials, int nb) {
  __shared__ int sums[256];
  int tid = threadIdx.x;
  int per = (nb + 255) / 256;
  int start = tid * per;
  int s = 0;
  for (int i = 0; i < per; ++i) {
    int idx = start + i;
    if (idx < nb) s += partials[idx];
  }
  sums[tid] = s;
  __syncthreads();
  for (int off = 1; off < 256; off <<= 1) {
    int t = (tid >= off) ? sums[tid - off] : 0;
    __syncthreads();
    sums[tid] += t;
    __syncthreads();
  }
  int excl = (tid == 0) ? 0 : sums[tid - 1];
  for (int i = 0; i < per; ++i) {
    int idx = start + i;
    if (idx < nb) {
      int t = partials[idx];
      partials[idx] = excl;
      excl += t;
    }
  }
}

__global__ void scan3_kernel(int* __restrict__ out, const int* __restrict__ partials, int n) {
  int base = blockIdx.x * 2048 + threadIdx.x * 8;
  int add = partials[blockIdx.x];
#pragma unroll
  for (int i = 0; i < 8; ++i) {
    int idx = base + i;
    if (idx < n) out[idx] += add;
  }
}

// seg_off sentinel + per-relation compact-row starts (run BEFORE mark_kernel)
__global__ void finalize_kernel(const int* __restrict__ cnt, int* __restrict__ seg_off,
                                const int* __restrict__ rowid, int* __restrict__ rowstart) {
  int t = threadIdx.x;
  if (t == 0) seg_off[NRR] = EE;
  if (t < 8) rowstart[t] = rowid[(size_t)t * NN];
  if (t == 8) rowstart[8] = rowid[NRR - 1] + (cnt[NRR - 1] > 0 ? 1 : 0);
}

__global__ void mark_kernel(const int* __restrict__ cnt, int* __restrict__ rowid, int n) {
  int i = blockIdx.x * blockDim.x + threadIdx.x;
  if (i < n && cnt[i] == 0) rowid[i] = -1;
}

__global__ void place_kernel(const int* __restrict__ srcv, const int* __restrict__ dstv,
                             const int* __restrict__ et, const int* __restrict__ seg_off,
                             int* __restrict__ cursor, int* __restrict__ sorted_src, int E) {
  int e = blockIdx.x * blockDim.x + threadIdx.x;
  if (e < E) {
    int p = et[e] * NN + dstv[e];
    int slot = seg_off[p] + atomicAdd(&cursor[p], 1);
    sorted_src[slot] = srcv[e];
  }
}

// ---------------- per-pair aggregation: tC[row] = bf16( (1/len) * sum xb[src] ) ----------------
__global__ __launch_bounds__(256) void agg_kernel(
    const ushort_t* __restrict__ xb, const int* __restrict__ seg_off,
    const int* __restrict__ rowid, const int* __restrict__ sorted_src,
    const int* __restrict__ rowstart, ushort_t* __restrict__ tC, int c) {
  int wv = (blockIdx.x * blockDim.x + threadIdx.x) >> 6;
  int lane = threadIdx.x & 63;
  if (wv >= 4 * NN) return;
  int p = c * 4 * NN + wv;
  int s0 = seg_off[p], s1 = seg_off[p + 1];
  if (s1 == s0) return;
  int row = rowid[p] - rowstart[c * 4];
  float a0 = 0.f, a1 = 0.f;
  for (int i = s0; i < s1; ++i) {
    int s = sorted_src[i];
    uint_t v = ((const uint_t*)(xb + (size_t)s * DD))[lane];
    a0 += b2f((ushort_t)(v & 0xffff));
    a1 += b2f((ushort_t)(v >> 16));
  }
  float sc = 1.0f / (float)(s1 - s0);
  uint_t o = (uint_t)f2b(a0 * sc) | ((uint_t)f2b(a1 * sc) << 16);
  ((uint_t*)(tC + (size_t)row * DD))[lane] = o;
}

// ---------------- per-dst combine: dacc += sum of active t rows; mode1 = relu+bf16 -> xbout ----------------
__global__ __launch_bounds__(256) void combine_kernel(
    float* __restrict__ dacc, const ushort_t* __restrict__ tC,
    const int* __restrict__ rowid, const int* __restrict__ rowstart,
    ushort_t* __restrict__ xbout, int c, int mode) {
  int wv = (blockIdx.x * blockDim.x + threadIdx.x) >> 6;
  int lane = threadIdx.x & 63;
  if (wv >= NN) return;
  int base = rowstart[c * 4];
  float2 v = ((float2*)(dacc + (size_t)wv * DD))[lane];
#pragma unroll
  for (int r = 0; r < 4; ++r) {
    int row = rowid[(size_t)(c * 4 + r) * NN + wv];
    if (row >= 0) {
      uint_t t = ((const uint_t*)(tC + (size_t)(row - base) * DD))[lane];
      v.x += b2f((ushort_t)(t & 0xffff));
      v.y += b2f((ushort_t)(t >> 16));
    }
  }
  if (mode == 0) {
    ((float2*)(dacc + (size_t)wv * DD))[lane] = v;
  } else {
    uint_t o = (uint_t)f2b(fmaxf(v.x, 0.f)) | ((uint_t)f2b(fmaxf(v.y, 0.f)) << 16);
    ((uint_t*)(xbout + (size_t)wv * DD))[lane] = o;
  }
}

static inline void launch_gemm_f32out(const ushort_t* A, const ushort_t* WT, const float* bias,
                                      float* C, int M, int K, hipStream_t stream) {
  hipLaunchKernelGGL((gemm_bf16<false>), dim3((M + 127) / 128), dim3(256), 0, stream,
                     A, WT, bias, (void*)C, M, K);
}
static inline void launch_gemm_b16out(const ushort_t* A, const ushort_t* WT, const float* bias,
                                      ushort_t* C, int M, int K, hipStream_t stream) {
  hipLaunchKernelGGL((gemm_bf16<true>), dim3((M + 127) / 128), dim3(256), 0, stream,
                     A, WT, bias, (void*)C, M, K);
}
static inline void launch_conv(const float* s, ushort_t* d, int n, hipStream_t stream) {
  int n4 = n / 4;
  hipLaunchKernelGGL(f32_to_bf16_kernel, dim3((n4 + 255) / 256), dim3(256), 0, stream, s, d, n4);
}
static inline void launch_wconv(const float* s, ushort_t* d, int K, int nmat, hipStream_t stream) {
  int total = nmat * K * 128;
  hipLaunchKernelGGL(wconv_kernel, dim3((total + 255) / 256), dim3(256), 0, stream, s, d, K, nmat);
}
static inline void launch_scan(const int* in, int* out, int* partials, int n, int binarize,
                               hipStream_t stream) {
  int nb = (n + 2047) / 2048;
  hipLaunchKernelGGL(scan1_kernel, dim3(nb), dim3(256), 0, stream, in, out, partials, n, binarize);
  hipLaunchKernelGGL(scan2_kernel, dim3(1), dim3(256), 0, stream, partials, nb);
  hipLaunchKernelGGL(scan3_kernel, dim3(nb), dim3(256), 0, stream, out, partials, n);
}

extern "C" void kernel_launch(void* const* d_in, const int* in_sizes, int n_in,
                              void* d_out, int out_size, void* d_ws, size_t ws_size,
                              hipStream_t stream) {
  const float* x_user = (const float*)d_in[0];
  const float* x_food = (const float*)d_in[1];
  const float* x_ing  = (const float*)d_in[2];
  const float* x_cat  = (const float*)d_in[3];
  const float* x_hab  = (const float*)d_in[4];
  const int*   eidx   = (const int*)d_in[5];
  const int*   etype  = (const int*)d_in[6];
  const float* Wu = (const float*)d_in[7];
  const float* bu = (const float*)d_in[8];
  const float* Wf = (const float*)d_in[9];
  const float* bfp = (const float*)d_in[10];
  const float* Wi = (const float*)d_in[11];
  const float* bi = (const float*)d_in[12];
  const float* Wc = (const float*)d_in[13];
  const float* bc = (const float*)d_in[14];
  const float* Wh = (const float*)d_in[15];
  const float* bh = (const float*)d_in[16];
  const float* W1    = (const float*)d_in[17];
  const float* root1 = (const float*)d_in[18];
  const float* bias1 = (const float*)d_in[19];
  const float* W2    = (const float*)d_in[20];
  const float* root2 = (const float*)d_in[21];
  const float* bias2 = (const float*)d_in[22];

  const int* src = eidx;
  const int* dst = eidx + EE;

  // ---- workspace layout (~124 MB) ----
  char* ws = (char*)d_ws;
  ushort_t* xb        = (ushort_t*)(ws);                    // 40,960,000 B
  ushort_t* tC        = (ushort_t*)(ws + 40960000);         // 64,000,000 B (CHUNK_CAP rows)
  int*      seg_off   = (int*)(ws + 104960000);             // (NRR+1)*4 -> 5,120,256
  int*      rowid     = (int*)(ws + 110080256);             // 5,120,000
  int*      cnt_i     = (int*)(ws + 115200256);             // 5,120,000 (also cursor)
  int*      sorted_src= (int*)(ws + 120320256);             // 2,400,000
  int*      rowstart  = (int*)(ws + 122720256);             // 64
  int*      partials  = (int*)(ws + 122720320);             // 4096
  ushort_t* wbuf      = (ushort_t*)(ws + 122724416);        // 753,664 B of bf16 weights

  ushort_t* WuT = wbuf;            // 128x256
  ushort_t* WfT = wbuf + 32768;    // 128x128
  ushort_t* WiT = wbuf + 49152;
  ushort_t* WcT = wbuf + 65536;    // 128x64
  ushort_t* WhT = wbuf + 73728;
  ushort_t* r1T = wbuf + 81920;    // 128x128
  ushort_t* r2T = wbuf + 98304;
  ushort_t* W1T = wbuf + 114688;   // 8 x 128x128
  ushort_t* W2T = wbuf + 245760;

  float* out = (float*)d_out;      // doubles as f32 conv accumulator

  // ---- weight conversion + transpose ----
  launch_wconv(Wu, WuT, 256, 1, stream);
  launch_wconv(Wf, WfT, 128, 1, stream);
  launch_wconv(Wi, WiT, 128, 1, stream);
  launch_wconv(Wc, WcT, 64, 1, stream);
  launch_wconv(Wh, WhT, 64, 1, stream);
  launch_wconv(root1, r1T, 128, 1, stream);
  launch_wconv(root2, r2T, 128, 1, stream);
  launch_wconv(W1, W1T, 128, 8, stream);
  launch_wconv(W2, W2T, 128, 8, stream);

  // ---- input projections -> xb (bf16 x_all); stage f32->bf16 inputs in tC (free now) ----
  ushort_t* stg = tC;
  launch_conv(x_user, stg, 50000 * 256, stream);
  launch_gemm_b16out(stg, WuT, bu, xb + (size_t)0 * DD, 50000, 256, stream);
  launch_conv(x_food, stg, 50000 * 128, stream);
  launch_conv(x_ing, stg + (size_t)50000 * 128, 50000 * 128, stream);
  launch_gemm_b16out(stg, WfT, bfp, xb + (size_t)50000 * DD, 50000, 128, stream);
  launch_gemm_b16out(stg + (size_t)50000 * 128, WiT, bi, xb + (size_t)100000 * DD, 50000, 128, stream);
  launch_conv(x_cat, stg, 5000 * 64, stream);
  launch_conv(x_hab, stg + (size_t)5000 * 64, 5000 * 64, stream);
  launch_gemm_b16out(stg, WcT, bc, xb + (size_t)150000 * DD, 5000, 64, stream);
  launch_gemm_b16out(stg + (size_t)5000 * 64, WhT, bh, xb + (size_t)155000 * DD, 5000, 64, stream);

  // ---- bucket edges by (relation, dst), shared by both convs ----
  hipMemsetAsync(cnt_i, 0, (size_t)NRR * 4, stream);
  hipLaunchKernelGGL(count_kernel, dim3((EE + 255) / 256), dim3(256), 0, stream,
                     dst, etype, cnt_i, EE);
  launch_scan(cnt_i, seg_off, partials, NRR, 0, stream);
  launch_scan(cnt_i, rowid, partials, NRR, 1, stream);
  hipLaunchKernelGGL(finalize_kernel, dim3(1), dim3(64), 0, stream,
                     cnt_i, seg_off, rowid, rowstart);
  hipLaunchKernelGGL(mark_kernel, dim3((NRR + 255) / 256), dim3(256), 0, stream,
                     cnt_i, rowid, NRR);
  hipMemsetAsync(cnt_i, 0, (size_t)NRR * 4, stream);  // reuse as cursor
  hipLaunchKernelGGL(place_kernel, dim3((EE + 255) / 256), dim3(256), 0, stream,
                     src, dst, etype, seg_off, cnt_i, sorted_src, EE);

  const dim3 aggGrid(4 * NN / 4);     // 4*NN waves, 4 waves/block
  const dim3 relGrid(512, 4);
  const dim3 cmbGrid(NN / 4);

  // ---- conv1: root -> out(f32); two 4-relation chunks; final writes relu'd bf16 into xb ----
  launch_gemm_f32out(xb, r1T, bias1, out, NN, 128, stream);
  for (int c = 0; c < 2; ++c) {
    hipLaunchKernelGGL(agg_kernel, aggGrid, dim3(256), 0, stream,
                       xb, seg_off, rowid, sorted_src, rowstart, tC, c);
    hipLaunchKernelGGL(gemm_rel, relGrid, dim3(256), 0, stream, tC, W1T, rowstart, c);
    hipLaunchKernelGGL(combine_kernel, cmbGrid, dim3(256), 0, stream,
                       out, tC, rowid, rowstart, xb, c, (c == 1) ? 1 : 0);
  }

  // ---- conv2: root -> out(f32); final leaves f32 in d_out ----
  launch_gemm_f32out(xb, r2T, bias2, out, NN, 128, stream);
  for (int c = 0; c < 2; ++c) {
    hipLaunchKernelGGL(agg_kernel, aggGrid, dim3(256), 0, stream,
                       xb, seg_off, rowid, sorted_src, rowstart, tC, c);
    hipLaunchKernelGGL(gemm_rel, relGrid, dim3(256), 0, stream, tC, W2T, rowstart, c);
    hipLaunchKernelGGL(combine_kernel, cmbGrid, dim3(256), 0, stream,
                       out, tC, rowid, rowstart, (ushort_t*)nullptr, c, 0);
  }
}

// Round 4
// 705.357 us; speedup vs baseline: 4.1697x; 1.3551x over previous
//
#include <hip/hip_runtime.h>

typedef unsigned short ushort_t;
typedef unsigned int uint_t;
typedef __attribute__((ext_vector_type(8))) __bf16 bf16x8;
typedef __attribute__((ext_vector_type(4))) float f32x4;
typedef __attribute__((ext_vector_type(4))) uint_t uint4v;

#define NN 160000
#define DD 128
#define EE 600000
#define RR 8
#define NRR (NN * RR)          // 1,280,000 pairs
// active pairs: E[distinct] = 1.28M*(1-e^-0.46875) ~= 479.1K (sigma ~0.5K)
#define CAP1 486000            // 1-chunk compact-row cap (~+13 sigma)
#define NEED1 184000000ULL     // ws bytes needed for 1-chunk layout

__device__ __forceinline__ ushort_t f2b(float f) {
  uint_t u = __float_as_uint(f);
  u = u + 0x7fffu + ((u >> 16) & 1u);   // round-nearest-even
  return (ushort_t)(u >> 16);
}
__device__ __forceinline__ float b2f(ushort_t u) {
  return __uint_as_float(((uint_t)u) << 16);
}

// ---------------- weight convert + transpose: src [nmat][K][128] f32 -> dst [nmat][128][K] bf16 ----------------
__global__ void wconv_kernel(const float* __restrict__ src,
                             ushort_t* __restrict__ dst, int K, int nmat) {
  int i = blockIdx.x * blockDim.x + threadIdx.x;
  int total = nmat * K * 128;
  if (i >= total) return;
  int m = i / (K * 128), rem = i % (K * 128);
  int k = rem / 128, n = rem % 128;
  dst[(size_t)m * 128 * K + (size_t)n * K + k] = f2b(src[i]);
}

// ---------------- MFMA GEMM: C[M x 128] = A[M x K] @ WT[128 x K](bf16) ----------------
// AF32: A is f32 (converted during staging); else bf16. OBF: bf16 output.
template <bool AF32, bool OBF>
__global__ __launch_bounds__(256, 2) void gemm_bf16(
    const void* __restrict__ Ain, const ushort_t* __restrict__ WT,
    const float* __restrict__ bias, void* __restrict__ Cout, int M, int K) {
  __shared__ ushort_t As[128 * 128];
  __shared__ ushort_t Ws[128 * 128];
  const int tid = threadIdx.x;
  const int bm = blockIdx.x * 128;
  const int wave = tid >> 6, lane = tid & 63;
  const int lr = lane & 15;
  const int lg = lane >> 4;

  f32x4 acc[2][8];
#pragma unroll
  for (int mt = 0; mt < 2; ++mt)
#pragma unroll
    for (int nt = 0; nt < 8; ++nt) acc[mt][nt] = {0.f, 0.f, 0.f, 0.f};

  for (int k0 = 0; k0 < K; k0 += 128) {
#pragma unroll
    for (int it = 0; it < 8; ++it) {
      int row = it * 16 + (tid >> 4);
      int c = tid & 15;
      uint4v val = {0, 0, 0, 0};
      int grow = bm + row, gk = k0 + c * 8;
      if (grow < M && gk < K) {
        if (AF32) {
          const float* ap = (const float*)Ain + (size_t)grow * K + gk;
          float4 v0 = *(const float4*)ap;
          float4 v1 = *(const float4*)(ap + 4);
          val[0] = (uint_t)f2b(v0.x) | ((uint_t)f2b(v0.y) << 16);
          val[1] = (uint_t)f2b(v0.z) | ((uint_t)f2b(v0.w) << 16);
          val[2] = (uint_t)f2b(v1.x) | ((uint_t)f2b(v1.y) << 16);
          val[3] = (uint_t)f2b(v1.z) | ((uint_t)f2b(v1.w) << 16);
        } else {
          val = *(const uint4v*)((const ushort_t*)Ain + (size_t)grow * K + gk);
        }
      }
      *(uint4v*)&As[row * 128 + ((c ^ (row & 7)) * 8)] = val;
    }
#pragma unroll
    for (int it = 0; it < 8; ++it) {
      int n = it * 16 + (tid >> 4);
      int c = tid & 15;
      uint4v val = {0, 0, 0, 0};
      int gk = k0 + c * 8;
      if (gk < K)
        val = *(const uint4v*)(WT + (size_t)n * K + gk);
      *(uint4v*)&Ws[n * 128 + ((c ^ (n & 7)) * 8)] = val;
    }
    __syncthreads();
#pragma unroll
    for (int ks = 0; ks < 4; ++ks) {
      int chunk = ks * 4 + lg;
      bf16x8 af[2], bfr[8];
#pragma unroll
      for (int mt = 0; mt < 2; ++mt) {
        int row = wave * 32 + mt * 16 + lr;
        af[mt] = *(const bf16x8*)&As[row * 128 + ((chunk ^ (row & 7)) * 8)];
      }
#pragma unroll
      for (int nt = 0; nt < 8; ++nt) {
        int n = nt * 16 + lr;
        bfr[nt] = *(const bf16x8*)&Ws[n * 128 + ((chunk ^ (n & 7)) * 8)];
      }
#pragma unroll
      for (int mt = 0; mt < 2; ++mt)
#pragma unroll
        for (int nt = 0; nt < 8; ++nt)
          acc[mt][nt] = __builtin_amdgcn_mfma_f32_16x16x32_bf16(
              af[mt], bfr[nt], acc[mt][nt], 0, 0, 0);
    }
    __syncthreads();
  }

  float bv[8];
#pragma unroll
  for (int nt = 0; nt < 8; ++nt) bv[nt] = bias ? bias[nt * 16 + lr] : 0.f;

#pragma unroll
  for (int mt = 0; mt < 2; ++mt) {
    int rbase = bm + wave * 32 + mt * 16 + lg * 4;
#pragma unroll
    for (int i = 0; i < 4; ++i) {
      int row = rbase + i;
      if (row >= M) continue;
#pragma unroll
      for (int nt = 0; nt < 8; ++nt) {
        int col = nt * 16 + lr;
        float v = acc[mt][nt][i] + bv[nt];
        if (OBF)
          ((ushort_t*)Cout)[(size_t)row * 128 + col] = f2b(v);
        else
          ((float*)Cout)[(size_t)row * 128 + col] = v;
      }
    }
  }
}

// ---------------- compact per-relation GEMM, K=128, in-place on tC (bf16) ----------------
__global__ __launch_bounds__(256, 2) void gemm_rel(
    ushort_t* __restrict__ tC, const ushort_t* __restrict__ WT_all,
    const int* __restrict__ rowstart, int relBase) {
  __shared__ ushort_t As[128 * 128];
  __shared__ ushort_t Ws[128 * 128];
  const int rel = relBase + blockIdx.y;
  const int base = rowstart[relBase];
  const int start = rowstart[rel] - base;
  const int end = rowstart[rel + 1] - base;
  const int bm = start + blockIdx.x * 128;
  if (bm >= end) return;
  const ushort_t* WT = WT_all + (size_t)rel * 16384;
  const int tid = threadIdx.x;
  const int wave = tid >> 6, lane = tid & 63;
  const int lr = lane & 15, lg = lane >> 4;

#pragma unroll
  for (int it = 0; it < 8; ++it) {
    int row = it * 16 + (tid >> 4);
    int cc = tid & 15;
    uint4v val = {0, 0, 0, 0};
    int grow = bm + row;
    if (grow < end)
      val = *(const uint4v*)(tC + (size_t)grow * 128 + cc * 8);
    *(uint4v*)&As[row * 128 + ((cc ^ (row & 7)) * 8)] = val;
  }
#pragma unroll
  for (int it = 0; it < 8; ++it) {
    int n = it * 16 + (tid >> 4);
    int cc = tid & 15;
    uint4v val = *(const uint4v*)(WT + (size_t)n * 128 + cc * 8);
    *(uint4v*)&Ws[n * 128 + ((cc ^ (n & 7)) * 8)] = val;
  }
  __syncthreads();

  f32x4 acc[2][8];
#pragma unroll
  for (int mt = 0; mt < 2; ++mt)
#pragma unroll
    for (int nt = 0; nt < 8; ++nt) acc[mt][nt] = {0.f, 0.f, 0.f, 0.f};

#pragma unroll
  for (int ks = 0; ks < 4; ++ks) {
    int chunk = ks * 4 + lg;
    bf16x8 af[2], bfr[8];
#pragma unroll
    for (int mt = 0; mt < 2; ++mt) {
      int row = wave * 32 + mt * 16 + lr;
      af[mt] = *(const bf16x8*)&As[row * 128 + ((chunk ^ (row & 7)) * 8)];
    }
#pragma unroll
    for (int nt = 0; nt < 8; ++nt) {
      int n = nt * 16 + lr;
      bfr[nt] = *(const bf16x8*)&Ws[n * 128 + ((chunk ^ (n & 7)) * 8)];
    }
#pragma unroll
    for (int mt = 0; mt < 2; ++mt)
#pragma unroll
      for (int nt = 0; nt < 8; ++nt)
        acc[mt][nt] = __builtin_amdgcn_mfma_f32_16x16x32_bf16(
            af[mt], bfr[nt], acc[mt][nt], 0, 0, 0);
  }
  __syncthreads();

#pragma unroll
  for (int mt = 0; mt < 2; ++mt) {
    int rbase = bm + wave * 32 + mt * 16 + lg * 4;
#pragma unroll
    for (int i = 0; i < 4; ++i) {
      int row = rbase + i;
      if (row >= end) continue;
#pragma unroll
      for (int nt = 0; nt < 8; ++nt)
        tC[(size_t)row * 128 + nt * 16 + lr] = f2b(acc[mt][nt][i]);
    }
  }
}

// ---------------- edge bucketing ----------------
__global__ void count_kernel(const int* __restrict__ dstv, const int* __restrict__ et,
                             int* __restrict__ cnt, int E) {
  int e = blockIdx.x * blockDim.x + threadIdx.x;
  if (e < E) atomicAdd(&cnt[(size_t)et[e] * NN + dstv[e]], 1);
}

__global__ __launch_bounds__(256) void scan1_kernel(const int* __restrict__ in, int* __restrict__ out,
                                                    int* __restrict__ partials, int n, int binarize) {
  __shared__ int sums[256];
  int tid = threadIdx.x;
  int base = blockIdx.x * 2048 + tid * 8;
  int v[8];
  int s = 0;
#pragma unroll
  for (int i = 0; i < 8; ++i) {
    int idx = base + i;
    int x = (idx < n) ? in[idx] : 0;
    if (binarize) x = (x > 0) ? 1 : 0;
    v[i] = s;
    s += x;
  }
  sums[tid] = s;
  __syncthreads();
  for (int off = 1; off < 256; off <<= 1) {
    int t = (tid >= off) ? sums[tid - off] : 0;
    __syncthreads();
    sums[tid] += t;
    __syncthreads();
  }
  int excl = (tid == 0) ? 0 : sums[tid - 1];
  if (tid == 255) partials[blockIdx.x] = sums[255];
#pragma unroll
  for (int i = 0; i < 8; ++i) {
    int idx = base + i;
    if (idx < n) out[idx] = excl + v[i];
  }
}

__global__ __launch_bounds__(256) void scan2_kernel(int* __restrict__ partials, int nb) {
  __shared__ int sums[256];
  int tid = threadIdx.x;
  int per = (nb + 255) / 256;
  int start = tid * per;
  int s = 0;
  for (int i = 0; i < per; ++i) {
    int idx = start + i;
    if (idx < nb) s += partials[idx];
  }
  sums[tid] = s;
  __syncthreads();
  for (int off = 1; off < 256; off <<= 1) {
    int t = (tid >= off) ? sums[tid - off] : 0;
    __syncthreads();
    sums[tid] += t;
    __syncthreads();
  }
  int excl = (tid == 0) ? 0 : sums[tid - 1];
  for (int i = 0; i < per; ++i) {
    int idx = start + i;
    if (idx < nb) {
      int t = partials[idx];
      partials[idx] = excl;
      excl += t;
    }
  }
}

__global__ void scan3_kernel(int* __restrict__ out, const int* __restrict__ partials, int n) {
  int base = blockIdx.x * 2048 + threadIdx.x * 8;
  int add = partials[blockIdx.x];
#pragma unroll
  for (int i = 0; i < 8; ++i) {
    int idx = base + i;
    if (idx < n) out[idx] += add;
  }
}

// seg_off sentinel + per-relation compact-row starts (run BEFORE mark_kernel)
__global__ void finalize_kernel(const int* __restrict__ cnt, int* __restrict__ seg_off,
                                const int* __restrict__ rowid, int* __restrict__ rowstart) {
  int t = threadIdx.x;
  if (t == 0) seg_off[NRR] = EE;
  if (t < 8) rowstart[t] = rowid[(size_t)t * NN];
  if (t == 8) rowstart[8] = rowid[NRR - 1] + (cnt[NRR - 1] > 0 ? 1 : 0);
}

__global__ void mark_kernel(const int* __restrict__ cnt, int* __restrict__ rowid, int n) {
  int i = blockIdx.x * blockDim.x + threadIdx.x;
  if (i < n && cnt[i] == 0) rowid[i] = -1;
}

__global__ void place_kernel(const int* __restrict__ srcv, const int* __restrict__ dstv,
                             const int* __restrict__ et, const int* __restrict__ seg_off,
                             int* __restrict__ cursor, int* __restrict__ sorted_src, int E) {
  int e = blockIdx.x * blockDim.x + threadIdx.x;
  if (e < E) {
    int p = et[e] * NN + dstv[e];
    int slot = seg_off[p] + atomicAdd(&cursor[p], 1);
    sorted_src[slot] = srcv[e];
  }
}

// ---------------- per-pair aggregation: tC[row] = bf16( (1/len) * sum xb[src] ) ----------------
// One 16-lane group per pair (4 pairs/wave -> 4 independent gather chains per instr).
__global__ __launch_bounds__(256) void agg_kernel(
    const ushort_t* __restrict__ xb, const int* __restrict__ seg_off,
    const int* __restrict__ rowid, const int* __restrict__ sorted_src,
    const int* __restrict__ rowstart, ushort_t* __restrict__ tC,
    int relBase, int npairs) {
  int g = (blockIdx.x * blockDim.x + threadIdx.x) >> 4;
  int sl = threadIdx.x & 15;
  if (g >= npairs) return;
  int p = relBase * NN + g;
  int s0 = seg_off[p], s1 = seg_off[p + 1];
  if (s1 == s0) return;
  int row = rowid[p] - rowstart[relBase];
  float a[8];
#pragma unroll
  for (int j = 0; j < 8; ++j) a[j] = 0.f;
  for (int i = s0; i < s1; ++i) {
    int s = sorted_src[i];
    uint4v v = *(const uint4v*)(xb + (size_t)s * DD + sl * 8);
#pragma unroll
    for (int j = 0; j < 4; ++j) {
      a[j * 2]     += b2f((ushort_t)(v[j] & 0xffff));
      a[j * 2 + 1] += b2f((ushort_t)(v[j] >> 16));
    }
  }
  float sc = 1.0f / (float)(s1 - s0);
  uint4v o;
#pragma unroll
  for (int j = 0; j < 4; ++j)
    o[j] = (uint_t)f2b(a[j * 2] * sc) | ((uint_t)f2b(a[j * 2 + 1] * sc) << 16);
  *(uint4v*)(tC + (size_t)row * DD + sl * 8) = o;
}

// ---------------- per-dst combine: v = dacc[wv] + sum active tC rows over [relBase, relBase+nrel) ----
// mode 0: write back f32 dacc;  mode 1: relu + bf16 -> xbout
__global__ __launch_bounds__(256) void combine_kernel(
    float* __restrict__ dacc, const ushort_t* __restrict__ tC,
    const int* __restrict__ rowid, const int* __restrict__ rowstart,
    ushort_t* __restrict__ xbout, int relBase, int nrel, int mode) {
  int wv = (blockIdx.x * blockDim.x + threadIdx.x) >> 6;
  int lane = threadIdx.x & 63;
  if (wv >= NN) return;
  int base = rowstart[relBase];
  float2 v = ((float2*)(dacc + (size_t)wv * DD))[lane];
  for (int r = 0; r < nrel; ++r) {
    int row = rowid[(size_t)(relBase + r) * NN + wv];
    if (row >= 0) {
      uint_t t = ((const uint_t*)(tC + (size_t)(row - base) * DD))[lane];
      v.x += b2f((ushort_t)(t & 0xffff));
      v.y += b2f((ushort_t)(t >> 16));
    }
  }
  if (mode == 0) {
    ((float2*)(dacc + (size_t)wv * DD))[lane] = v;
  } else {
    uint_t o = (uint_t)f2b(fmaxf(v.x, 0.f)) | ((uint_t)f2b(fmaxf(v.y, 0.f)) << 16);
    ((uint_t*)(xbout + (size_t)wv * DD))[lane] = o;
  }
}

static inline void launch_gemm_f32in_b16out(const float* A, const ushort_t* WT, const float* bias,
                                            ushort_t* C, int M, int K, hipStream_t stream) {
  hipLaunchKernelGGL((gemm_bf16<true, true>), dim3((M + 127) / 128), dim3(256), 0, stream,
                     (const void*)A, WT, bias, (void*)C, M, K);
}
static inline void launch_gemm_b16in_f32out(const ushort_t* A, const ushort_t* WT, const float* bias,
                                            float* C, int M, int K, hipStream_t stream) {
  hipLaunchKernelGGL((gemm_bf16<false, false>), dim3((M + 127) / 128), dim3(256), 0, stream,
                     (const void*)A, WT, bias, (void*)C, M, K);
}
static inline void launch_wconv(const float* s, ushort_t* d, int K, int nmat, hipStream_t stream) {
  int total = nmat * K * 128;
  hipLaunchKernelGGL(wconv_kernel, dim3((total + 255) / 256), dim3(256), 0, stream, s, d, K, nmat);
}
static inline void launch_scan(const int* in, int* out, int* partials, int n, int binarize,
                               hipStream_t stream) {
  int nb = (n + 2047) / 2048;
  hipLaunchKernelGGL(scan1_kernel, dim3(nb), dim3(256), 0, stream, in, out, partials, n, binarize);
  hipLaunchKernelGGL(scan2_kernel, dim3(1), dim3(256), 0, stream, partials, nb);
  hipLaunchKernelGGL(scan3_kernel, dim3(nb), dim3(256), 0, stream, out, partials, n);
}

extern "C" void kernel_launch(void* const* d_in, const int* in_sizes, int n_in,
                              void* d_out, int out_size, void* d_ws, size_t ws_size,
                              hipStream_t stream) {
  const float* x_user = (const float*)d_in[0];
  const float* x_food = (const float*)d_in[1];
  const float* x_ing  = (const float*)d_in[2];
  const float* x_cat  = (const float*)d_in[3];
  const float* x_hab  = (const float*)d_in[4];
  const int*   eidx   = (const int*)d_in[5];
  const int*   etype  = (const int*)d_in[6];
  const float* Wu = (const float*)d_in[7];
  const float* bu = (const float*)d_in[8];
  const float* Wf = (const float*)d_in[9];
  const float* bfp = (const float*)d_in[10];
  const float* Wi = (const float*)d_in[11];
  const float* bi = (const float*)d_in[12];
  const float* Wc = (const float*)d_in[13];
  const float* bc = (const float*)d_in[14];
  const float* Wh = (const float*)d_in[15];
  const float* bh = (const float*)d_in[16];
  const float* W1    = (const float*)d_in[17];
  const float* root1 = (const float*)d_in[18];
  const float* bias1 = (const float*)d_in[19];
  const float* W2    = (const float*)d_in[20];
  const float* root2 = (const float*)d_in[21];
  const float* bias2 = (const float*)d_in[22];

  const int* src = eidx;
  const int* dst = eidx + EE;

  const bool one_chunk = (ws_size >= NEED1);
  const size_t tc_bytes = one_chunk ? (size_t)CAP1 * 256 : 64000000ULL;

  // ---- workspace layout ----
  char* ws = (char*)d_ws;
  size_t off = 0;
  ushort_t* xb = (ushort_t*)(ws + off);         off += 40960000;
  ushort_t* tC = (ushort_t*)(ws + off);         off += tc_bytes;
  int* seg_off = (int*)(ws + off);              off += (size_t)(NRR + 1 + 63) / 64 * 64 * 4;
  int* rowid   = (int*)(ws + off);              off += (size_t)NRR * 4;
  int* cnt_i   = (int*)(ws + off);              off += (size_t)NRR * 4;   // also cursor
  int* sorted_src = (int*)(ws + off);           off += (size_t)EE * 4;
  int* rowstart   = (int*)(ws + off);           off += 64;
  int* partials   = (int*)(ws + off);           off += 4096;
  ushort_t* wbuf  = (ushort_t*)(ws + off);

  ushort_t* WuT = wbuf;            // 128x256
  ushort_t* WfT = wbuf + 32768;    // 128x128
  ushort_t* WiT = wbuf + 49152;
  ushort_t* WcT = wbuf + 65536;    // 128x64
  ushort_t* WhT = wbuf + 73728;
  ushort_t* r1T = wbuf + 81920;    // 128x128
  ushort_t* r2T = wbuf + 98304;
  ushort_t* W1T = wbuf + 114688;   // 8 x 128x128
  ushort_t* W2T = wbuf + 245760;

  float* out = (float*)d_out;      // doubles as f32 conv accumulator

  // ---- weight conversion + transpose ----
  launch_wconv(Wu, WuT, 256, 1, stream);
  launch_wconv(Wf, WfT, 128, 1, stream);
  launch_wconv(Wi, WiT, 128, 1, stream);
  launch_wconv(Wc, WcT, 64, 1, stream);
  launch_wconv(Wh, WhT, 64, 1, stream);
  launch_wconv(root1, r1T, 128, 1, stream);
  launch_wconv(root2, r2T, 128, 1, stream);
  launch_wconv(W1, W1T, 128, 8, stream);
  launch_wconv(W2, W2T, 128, 8, stream);

  // ---- input projections -> xb (bf16 x_all); f32->bf16 fused into GEMM A-staging ----
  launch_gemm_f32in_b16out(x_user, WuT, bu, xb + (size_t)0 * DD,      50000, 256, stream);
  launch_gemm_f32in_b16out(x_food, WfT, bfp, xb + (size_t)50000 * DD, 50000, 128, stream);
  launch_gemm_f32in_b16out(x_ing,  WiT, bi, xb + (size_t)100000 * DD, 50000, 128, stream);
  launch_gemm_f32in_b16out(x_cat,  WcT, bc, xb + (size_t)150000 * DD, 5000,  64,  stream);
  launch_gemm_f32in_b16out(x_hab,  WhT, bh, xb + (size_t)155000 * DD, 5000,  64,  stream);

  // ---- bucket edges by (relation, dst), shared by both convs ----
  hipMemsetAsync(cnt_i, 0, (size_t)NRR * 4, stream);
  hipLaunchKernelGGL(count_kernel, dim3((EE + 255) / 256), dim3(256), 0, stream,
                     dst, etype, cnt_i, EE);
  launch_scan(cnt_i, seg_off, partials, NRR, 0, stream);
  launch_scan(cnt_i, rowid, partials, NRR, 1, stream);
  hipLaunchKernelGGL(finalize_kernel, dim3(1), dim3(64), 0, stream,
                     cnt_i, seg_off, rowid, rowstart);
  hipLaunchKernelGGL(mark_kernel, dim3((NRR + 255) / 256), dim3(256), 0, stream,
                     cnt_i, rowid, NRR);
  hipMemsetAsync(cnt_i, 0, (size_t)NRR * 4, stream);  // reuse as cursor
  hipLaunchKernelGGL(place_kernel, dim3((EE + 255) / 256), dim3(256), 0, stream,
                     src, dst, etype, seg_off, cnt_i, sorted_src, EE);

  const int nchunks = one_chunk ? 1 : 2;
  const int rpc = RR / nchunks;                 // relations per chunk
  const int npairs = rpc * NN;
  const dim3 aggGrid((npairs + 4095) / 4096);   // 16 pairs/wave-group *16 groups... 256thr=16 groups
  const dim3 relGrid(512, rpc);
  const dim3 cmbGrid(NN / 4);

  // ---- conv1 ----
  launch_gemm_b16in_f32out(xb, r1T, bias1, out, NN, 128, stream);
  for (int c = 0; c < nchunks; ++c) {
    hipLaunchKernelGGL(agg_kernel, dim3((npairs * 16 + 255) / 256), dim3(256), 0, stream,
                       xb, seg_off, rowid, sorted_src, rowstart, tC, c * rpc, npairs);
    hipLaunchKernelGGL(gemm_rel, relGrid, dim3(256), 0, stream, tC, W1T, rowstart, c * rpc);
    hipLaunchKernelGGL(combine_kernel, cmbGrid, dim3(256), 0, stream,
                       out, tC, rowid, rowstart, xb, c * rpc, rpc,
                       (c == nchunks - 1) ? 1 : 0);
  }

  // ---- conv2 ----
  launch_gemm_b16in_f32out(xb, r2T, bias2, out, NN, 128, stream);
  for (int c = 0; c < nchunks; ++c) {
    hipLaunchKernelGGL(agg_kernel, dim3((npairs * 16 + 255) / 256), dim3(256), 0, stream,
                       xb, seg_off, rowid, sorted_src, rowstart, tC, c * rpc, npairs);
    hipLaunchKernelGGL(gemm_rel, relGrid, dim3(256), 0, stream, tC, W2T, rowstart, c * rpc);
    hipLaunchKernelGGL(combine_kernel, cmbGrid, dim3(256), 0, stream,
                       out, tC, rowid, rowstart, (ushort_t*)nullptr, c * rpc, rpc, 0);
  }
}